// Round 3
// baseline (2027.543 us; speedup 1.0000x reference)
//
#include <hip/hip_runtime.h>
#include <hip/hip_cooperative_groups.h>
#include <math.h>

namespace cg = cooperative_groups;

#define NN 50000
#define FF 96
#define EE 800000
#define OF 384          // 4 * FF concatenated output width
#define GB 3125         // 16 rows per tile (gat + layer0); GB*16 == NN exactly
#define FBU 48          // uints per bf16 feature row (96 bf16 = 192 B)
#define CAP 64          // slots per row (max deg ~35 for this graph)
#define BSH 6           // bucket = row >> 6  (64 rows per bucket)
#define BROWS 64        // rows per bucket
#define NB 782          // row buckets (ceil(50000/64))
#define BCAP 1536       // slots per bucket (mean 1023, +16 sigma safe)
#define P1 800          // phase-1 bucketing chunks
#define CHUNK 1000      // edges per phase-1 chunk (800 * 1000 == EE)
#define SHARD 12500     // col shard width: 4 shards x 2.4 MB bf16 rows (XCD L2)
#define GRID 2048       // cooperative grid: 8 blocks/CU x 256 CU (VGPR<=64, LDS 10.2KB)
#define SHBYTES 10240   // union LDS: phase1 3*NB*4=9384 | phase2 8192+1024+1024

__device__ __forceinline__ float grp_sum(float v) {          // 16-lane group
    for (int m = 8; m >= 1; m >>= 1) v += __shfl_xor(v, m, 64);
    return v;
}
__device__ __forceinline__ float grp_max(float v) {
    for (int m = 8; m >= 1; m >>= 1) v = fmaxf(v, __shfl_xor(v, m, 64));
    return v;
}
__device__ __forceinline__ float lrelu(float x) { return x > 0.f ? x : 0.2f * x; }
__device__ __forceinline__ void online_upd(float s, float& m, float& d) {
    float nm = fmaxf(m, s);
    d = d * __expf(m - nm) + __expf(s - nm);
    m = nm;
}
// bf16 pack/unpack (uint k holds elems 2k lo16, 2k+1 hi16; RNE rounding)
__device__ __forceinline__ float bf_lo(unsigned u) { return __uint_as_float(u << 16); }
__device__ __forceinline__ float bf_hi(unsigned u) { return __uint_as_float(u & 0xffff0000u); }
__device__ __forceinline__ unsigned pack_bf(float a, float b) {
    unsigned ua = __float_as_uint(a), ub = __float_as_uint(b);
    ua = ua + 0x7fffu + ((ua >> 16) & 1u);
    ub = ub + 0x7fffu + ((ub >> 16) & 1u);
    return (ua >> 16) | (ub & 0xffff0000u);
}

// lane lg (<12) holds row elems 8lg..8lg+7 (two float4s / one uint4)
__device__ __forceinline__ float grp_dot8(const float* a,
                                          const float* __restrict__ kf, int lg) {
    float s = 0.f;
    if (lg < 12) {
        float4 w0 = ((const float4*)kf)[2 * lg];
        float4 w1 = ((const float4*)kf)[2 * lg + 1];
        s = a[0] * w0.x + a[1] * w0.y + a[2] * w0.z + a[3] * w0.w +
            a[4] * w1.x + a[5] * w1.y + a[6] * w1.z + a[7] * w1.w;
    }
    return grp_sum(s);
}

// ---------------- phase bodies (shared by fused + legacy kernels) ----------

__device__ __forceinline__ void p1_chunk(int p, const int2* __restrict__ idx2,
                                         int* __restrict__ bfill,
                                         unsigned* __restrict__ buckets,
                                         int* cnt, int* basearr, int* ofs, int tid) {
    int start = p * CHUNK, end = min(start + CHUNK, EE);
    for (int b = tid; b < NB; b += 256) { cnt[b] = 0; ofs[b] = 0; }
    __syncthreads();
    for (int e = start + tid; e < end; e += 256)
        atomicAdd(&cnt[idx2[e].x >> BSH], 1);
    __syncthreads();
    for (int b = tid; b < NB; b += 256)
        basearr[b] = cnt[b] ? atomicAdd(&bfill[b], cnt[b]) : 0;
    __syncthreads();
    for (int e = start + tid; e < end; e += 256) {
        int2 q = idx2[e];
        int b = q.x >> BSH;
        int slot = basearr[b] + atomicAdd(&ofs[b], 1);
        if (slot < BCAP)
            buckets[(size_t)b * BCAP + slot] =
                ((unsigned)(q.x & (BROWS - 1)) << 16) | (unsigned)q.y;
    }
    __syncthreads();   // LDS reuse safety across strided iterations
}

template<int BF>
__device__ __forceinline__ void l0_tile(int t, const float* __restrict__ node_f,
                                        const int* __restrict__ sidx,
                                        const float* __restrict__ sval,
                                        float* __restrict__ out,
                                        unsigned* __restrict__ fb,
                                        const float* __restrict__ ks,
                                        const float* __restrict__ kn,
                                        float2* __restrict__ ass,
                                        float2* __restrict__ ann, int tid) {
    int g = tid >> 4, lg = tid & 15;
    int n = t * 16 + g;
    if (n >= NN) return;
    int sr = sidx[2 * n];
    int sc = sidx[2 * n + 1];
    float v = sval[n];
    float a[8] = {0.f, 0.f, 0.f, 0.f, 0.f, 0.f, 0.f, 0.f};
    if (lg < 12) {
        const float4* xr4 = (const float4*)(node_f + (size_t)sc * FF);
        float4 x0 = xr4[2 * lg], x1 = xr4[2 * lg + 1];
        a[0] = fmaxf(v * x0.x, 0.f); a[1] = fmaxf(v * x0.y, 0.f);
        a[2] = fmaxf(v * x0.z, 0.f); a[3] = fmaxf(v * x0.w, 0.f);
        a[4] = fmaxf(v * x1.x, 0.f); a[5] = fmaxf(v * x1.y, 0.f);
        a[6] = fmaxf(v * x1.z, 0.f); a[7] = fmaxf(v * x1.w, 0.f);
        float4* op4 = (float4*)(out + (size_t)sr * OF);
        op4[2 * lg]     = make_float4(a[0], a[1], a[2], a[3]);
        op4[2 * lg + 1] = make_float4(a[4], a[5], a[6], a[7]);
        if (BF) {
            uint4 p;
            p.x = pack_bf(a[0], a[1]); p.y = pack_bf(a[2], a[3]);
            p.z = pack_bf(a[4], a[5]); p.w = pack_bf(a[6], a[7]);
            ((uint4*)(fb + (size_t)sr * FBU))[lg] = p;
        }
    }
    float p0 = grp_dot8(a, ks, lg);
    float p1 = grp_dot8(a, ks + FF, lg);
    float p2 = grp_dot8(a, kn, lg);
    float p3 = grp_dot8(a, kn + FF, lg);
    if (lg == 0) {
        ass[sr] = make_float2(p0, p1);
        ann[sr] = make_float2(p2, p3);
    }
}

__device__ __forceinline__ void b2c_tile(int b, const int* __restrict__ bfill,
                                         const unsigned* __restrict__ buckets,
                                         int* __restrict__ fill,
                                         unsigned short* __restrict__ csr,
                                         unsigned short* lcsr, int* lcnt, int* loff,
                                         int tid) {
    lcnt[tid] = 0;                                   // 64*4 == 256 entries
    __syncthreads();
    int cnt = min(bfill[b], BCAP);
    const unsigned* bp = buckets + (size_t)b * BCAP;
    for (int i = tid; i < cnt; i += 256) {       // pass 1: count per (row,shard)
        unsigned u = bp[i];
        atomicAdd(&lcnt[(u >> 16) * 4 + (int)((u & 0xffffu) / SHARD)], 1);
    }
    __syncthreads();
    if (tid < BROWS) {
        int c0 = lcnt[tid * 4], c1 = lcnt[tid * 4 + 1];
        int c2 = lcnt[tid * 4 + 2], c3 = lcnt[tid * 4 + 3];
        loff[tid * 4] = 0;
        loff[tid * 4 + 1] = c0;
        loff[tid * 4 + 2] = c0 + c1;
        loff[tid * 4 + 3] = c0 + c1 + c2;
        int r = b * BROWS + tid;
        if (r < NN) fill[r] = min(c0 + c1 + c2 + c3, CAP);
        lcnt[tid * 4] = 0; lcnt[tid * 4 + 1] = 0;
        lcnt[tid * 4 + 2] = 0; lcnt[tid * 4 + 3] = 0;
    }
    __syncthreads();
    for (int i = tid; i < cnt; i += 256) {       // pass 2: shard-sorted place
        unsigned u = bp[i];
        int lr = u >> 16, col = u & 0xffffu, cls = col / SHARD;
        int pos = loff[lr * 4 + cls] + atomicAdd(&lcnt[lr * 4 + cls], 1);
        if (pos < CAP) lcsr[lr * CAP + pos] = (unsigned short)col;
    }
    __syncthreads();
    const uint4* src = (const uint4*)lcsr;
    uint4* dst = (uint4*)(csr + (size_t)b * BROWS * CAP);
    for (int i = tid; i < BROWS * CAP / 8; i += 256) dst[i] = src[i];
    __syncthreads();   // LDS reuse safety across strided iterations
}

// ---- aggregation helper: one dwordx4 per edge per lane (lanes 0-11) -------
template<int BF>
__device__ __forceinline__ void agg_chunk(float cj, int colj, int nj, int gbase,
                                          const float* __restrict__ feats,
                                          const unsigned* __restrict__ fb, int lg,
                                          float* a) {
#pragma unroll 8
    for (int k = 0; k < nj; ++k) {
        float cc = __shfl(cj, gbase + k, 64);
        int col  = __shfl(colj, gbase + k, 64);
        if (lg < 12) {
            if (BF) {
                uint4 q = ((const uint4*)(fb + (size_t)col * FBU))[lg];
                a[0] += cc * bf_lo(q.x); a[1] += cc * bf_hi(q.x);
                a[2] += cc * bf_lo(q.y); a[3] += cc * bf_hi(q.y);
                a[4] += cc * bf_lo(q.z); a[5] += cc * bf_hi(q.z);
                a[6] += cc * bf_lo(q.w); a[7] += cc * bf_hi(q.w);
            } else {
                const float4* vp = (const float4*)(feats + (size_t)col * OF);
                float4 v0 = vp[2 * lg], v1 = vp[2 * lg + 1];
                a[0] += cc * v0.x; a[1] += cc * v0.y;
                a[2] += cc * v0.z; a[3] += cc * v0.w;
                a[4] += cc * v1.x; a[5] += cc * v1.y;
                a[6] += cc * v1.z; a[7] += cc * v1.w;
            }
        }
    }
}

template<int BF>
__device__ __forceinline__ void gat_tile(int t, int l, float* __restrict__ out,
                                         const int* __restrict__ fill,
                                         const unsigned short* __restrict__ csr,
                                         const float2* __restrict__ ass,
                                         const float2* __restrict__ ann,
                                         const unsigned* __restrict__ fb_in,
                                         unsigned* __restrict__ fb_out,
                                         const float* __restrict__ ks,
                                         const float* __restrict__ kn,
                                         float2* __restrict__ ass_out,
                                         float2* __restrict__ ann_out,
                                         int write_dots, int tid) {
    int g = tid >> 4, lg = tid & 15;
    int gbase = (g & 3) * 16;                 // group base lane within wave
    int r = t * 16 + g;
    if (r >= NN) return;
    int deg = fill[r];
    const unsigned short* crow = csr + (size_t)r * CAP;
    const float* feats = out + l * FF;        // fp32 fallback source
    float2 as_r = ass[r];

    // ---- pass A: scores; chunks 0,1 (deg<=32, ~all rows) cached in scalars
    float m0 = -1e30f, m1 = -1e30f, d0 = 0.f, d1 = 0.f;
    int   c0col = 0, c1col = 0;
    float c0s0 = -1e30f, c0s1 = -1e30f, c1s0 = -1e30f, c1s1 = -1e30f;
    if (lg < deg) {
        int c = crow[lg];
        float2 an = ann[c];
        c0col = c;
        c0s0 = lrelu(as_r.x + an.x);
        c0s1 = lrelu(as_r.y + an.y);
        online_upd(c0s0, m0, d0);
        online_upd(c0s1, m1, d1);
    }
    if (deg > 16) {
        int j = 16 + lg;
        if (j < deg) {
            int c = crow[j];
            float2 an = ann[c];
            c1col = c;
            c1s0 = lrelu(as_r.x + an.x);
            c1s1 = lrelu(as_r.y + an.y);
            online_upd(c1s0, m0, d0);
            online_upd(c1s1, m1, d1);
        }
        for (int j0 = 32; j0 < deg; j0 += 16) {
            int jj = j0 + lg;
            if (jj < deg) {
                int c = crow[jj];
                float2 an = ann[c];
                online_upd(lrelu(as_r.x + an.x), m0, d0);
                online_upd(lrelu(as_r.y + an.y), m1, d1);
            }
        }
    }
    float M0 = grp_max(m0), M1 = grp_max(m1);
    d0 = grp_sum(d0 * __expf(m0 - M0));
    d1 = grp_sum(d1 * __expf(m1 - M1));
    float inv0 = d0 > 0.f ? 0.5f / d0 : 0.f;  // 0.5 = mean over 2 heads
    float inv1 = d1 > 0.f ? 0.5f / d1 : 0.f;

    // ---- pass B: aggregate (one 16B load per edge per lane, lanes 0-11)
    float a[8] = {0.f, 0.f, 0.f, 0.f, 0.f, 0.f, 0.f, 0.f};
    {
        float cj = __expf(c0s0 - M0) * inv0 + __expf(c0s1 - M1) * inv1;
        agg_chunk<BF>(cj, c0col, min(deg, 16), gbase, feats, fb_in, lg, a);
    }
    if (deg > 16) {
        float cj = __expf(c1s0 - M0) * inv0 + __expf(c1s1 - M1) * inv1;
        agg_chunk<BF>(cj, c1col, min(deg - 16, 16), gbase, feats, fb_in, lg, a);
        for (int j0 = 32; j0 < deg; j0 += 16) {
            float cjr = 0.f; int colr = 0;
            int jj = j0 + lg;
            if (jj < deg) {
                int c = crow[jj];
                float2 an = ann[c];
                cjr = __expf(lrelu(as_r.x + an.x) - M0) * inv0 +
                      __expf(lrelu(as_r.y + an.y) - M1) * inv1;
                colr = c;
            }
            agg_chunk<BF>(cjr, colr, min(deg - j0, 16), gbase, feats, fb_in, lg, a);
        }
    }

#pragma unroll
    for (int i = 0; i < 8; ++i) a[i] = fmaxf(a[i], 0.f);
    if (lg < 12) {
        float4* op4 = (float4*)(out + (size_t)r * OF + (l + 1) * FF);
        op4[2 * lg]     = make_float4(a[0], a[1], a[2], a[3]);
        op4[2 * lg + 1] = make_float4(a[4], a[5], a[6], a[7]);
        if (BF && fb_out) {
            uint4 p;
            p.x = pack_bf(a[0], a[1]); p.y = pack_bf(a[2], a[3]);
            p.z = pack_bf(a[4], a[5]); p.w = pack_bf(a[6], a[7]);
            ((uint4*)(fb_out + (size_t)r * FBU))[lg] = p;
        }
    }

    if (write_dots) {
        float p0 = grp_dot8(a, ks, lg);
        float p1 = grp_dot8(a, ks + FF, lg);
        float p2 = grp_dot8(a, kn, lg);
        float p3 = grp_dot8(a, kn + FF, lg);
        if (lg == 0) {
            ass_out[r] = make_float2(p0, p1);
            ann_out[r] = make_float2(p2, p3);
        }
    }
}

// ---------------- fused persistent cooperative kernel ----------------------
// One dispatch, STATIC strided tile assignment (round 2's global atomic
// work-queue serialized at ~100ns/grab across XCDs => 1.18ms; removed).
// 2048 blocks = 8/CU co-resident (VGPR<=64 via launch_bounds, LDS 10.2KB).
template<int BF>
__global__ __launch_bounds__(256, 8) void fused_gat(
    const float* __restrict__ node_f, const int* __restrict__ sidx,
    const float* __restrict__ sval, float* __restrict__ out,
    const float* __restrict__ ks, const float* __restrict__ kn,
    const int2* __restrict__ idx2, int* __restrict__ bfill,
    unsigned* __restrict__ buckets, int* __restrict__ fill,
    unsigned short* __restrict__ csr,
    float2* ass_a, float2* ann_a, float2* ass_b, float2* ann_b,
    unsigned* fb_a, unsigned* fb_b) {
    cg::grid_group grid = cg::this_grid();
    int tid = threadIdx.x;
    int bid = blockIdx.x;
    __shared__ alignas(16) char shraw[SHBYTES];
    int* cnt = (int*)shraw;
    int* basearr = cnt + NB;
    int* ofs = basearr + NB;
    unsigned short* lcsr = (unsigned short*)shraw;
    int* lcnt = (int*)(shraw + BROWS * CAP * 2);
    int* loff = lcnt + BROWS * 4;

    // ---- phase A: edge bucketing (P1 units) + layer 0 (GB units)
    for (int u = bid; u < P1 + GB; u += GRID) {
        if (u < P1)
            p1_chunk(u, idx2, bfill, buckets, cnt, basearr, ofs, tid);
        else
            l0_tile<BF>(u - P1, node_f, sidx, sval, out, fb_a, ks, kn,
                        ass_a, ann_a, tid);
    }
    __threadfence();
    grid.sync();

    // ---- phase B: buckets -> padded, shard-sorted CSR
    for (int b = bid; b < NB; b += GRID)
        b2c_tile(b, bfill, buckets, fill, csr, lcsr, lcnt, loff, tid);
    __threadfence();
    grid.sync();

    // ---- phases C/D/E: 3 GAT layers, ping-pong dot/feature buffers
    float2* as = ass_a;  float2* an = ann_a;
    float2* aso = ass_b; float2* ano = ann_b;
    unsigned* fin = fb_a; unsigned* fout = fb_b;
#pragma unroll 1
    for (int l = 0; l < 3; ++l) {
        for (int t = bid; t < GB; t += GRID)
            gat_tile<BF>(t, l, out, fill, csr, as, an, fin,
                         (l < 2) ? fout : (unsigned*)nullptr,
                         ks, kn, aso, ano, l < 2, tid);
        if (l < 2) { __threadfence(); grid.sync(); }
        float2* t1 = as; as = aso; aso = t1;
        float2* t2 = an; an = ano; ano = t2;
        unsigned* t3 = fin; fin = fout; fout = t3;
    }
}

// ---------------- legacy separate-kernel path (fallback) -------------------
template<int BF>
__global__ __launch_bounds__(256) void l0_phase1(
    const float* __restrict__ node_f, const int* __restrict__ sidx,
    const float* __restrict__ sval, float* __restrict__ out,
    unsigned* __restrict__ fb, const float* __restrict__ ks,
    const float* __restrict__ kn, float2* __restrict__ ass,
    float2* __restrict__ ann, const int2* __restrict__ idx2,
    int* __restrict__ bfill, unsigned* __restrict__ buckets) {
    __shared__ alignas(16) char shraw[12 * NB];
    int tid = threadIdx.x;
    if (blockIdx.x < P1) {
        int* cnt = (int*)shraw;
        p1_chunk(blockIdx.x, idx2, bfill, buckets, cnt, cnt + NB, cnt + 2 * NB, tid);
        return;
    }
    l0_tile<BF>(blockIdx.x - P1, node_f, sidx, sval, out, fb, ks, kn, ass, ann, tid);
}

__global__ __launch_bounds__(256) void bucket2csr_k(const int* __restrict__ bfill,
                                                    const unsigned* __restrict__ buckets,
                                                    int* __restrict__ fill,
                                                    unsigned short* __restrict__ csr) {
    __shared__ alignas(16) char shraw[SHBYTES];
    unsigned short* lcsr = (unsigned short*)shraw;
    int* lcnt = (int*)(shraw + BROWS * CAP * 2);
    int* loff = lcnt + BROWS * 4;
    b2c_tile(blockIdx.x, bfill, buckets, fill, csr, lcsr, lcnt, loff, threadIdx.x);
}

template<int BF>
__global__ __launch_bounds__(256) void gat_layer(float* __restrict__ out, int l,
                                                 const int* __restrict__ fill,
                                                 const unsigned short* __restrict__ csr,
                                                 const float2* __restrict__ ass,
                                                 const float2* __restrict__ ann,
                                                 const unsigned* __restrict__ fb_in,
                                                 unsigned* __restrict__ fb_out,
                                                 const float* __restrict__ ks,
                                                 const float* __restrict__ kn,
                                                 float2* __restrict__ ass_out,
                                                 float2* __restrict__ ann_out,
                                                 int write_dots) {
    gat_tile<BF>(blockIdx.x, l, out, fill, csr, ass, ann, fb_in, fb_out,
                 ks, kn, ass_out, ann_out, write_dots, threadIdx.x);
}

extern "C" void kernel_launch(void* const* d_in, const int* in_sizes, int n_in,
                              void* d_out, int out_size, void* d_ws, size_t ws_size,
                              hipStream_t stream) {
    const float* node_f  = (const float*)d_in[0];
    const int*   adj_idx = (const int*)d_in[1];   // (1,E,2) [row,col] int32
    const int*   sidx    = (const int*)d_in[2];   // (N,2)
    const float* sval    = (const float*)d_in[3]; // (N,)
    const float* k_self  = (const float*)d_in[4]; // (2,96)
    const float* k_neigh = (const float*)d_in[5]; // (2,96)
    float* out = (float*)d_out;                   // (N, 384)
    const int2* idx2 = (const int2*)adj_idx;

    char* w = (char*)d_ws;
    auto alloc = [&](size_t bytes) {
        char* p = w;
        w += (bytes + 255) & ~(size_t)255;
        return p;
    };
    int*            fill    = (int*)alloc((size_t)NN * 4);
    unsigned short* csr     = (unsigned short*)alloc((size_t)NB * BROWS * CAP * 2);
    int*            bfill   = (int*)alloc((size_t)NB * 4);
    unsigned*       buckets = (unsigned*)alloc((size_t)NB * BCAP * 4);
    float2*         ass_a   = (float2*)alloc((size_t)NN * 8);
    float2*         ann_a   = (float2*)alloc((size_t)NN * 8);
    float2*         ass_b   = (float2*)alloc((size_t)NN * 8);
    float2*         ann_b   = (float2*)alloc((size_t)NN * 8);
    unsigned*       fb_a    = (unsigned*)alloc((size_t)NN * FBU * 4);
    unsigned*       fb_b    = (unsigned*)alloc((size_t)NN * FBU * 4);
    // bf16-gather path only if the workspace actually holds the two fb buffers
    bool bf = (size_t)(w - (char*)d_ws) <= ws_size;

    hipMemsetAsync(bfill, 0, (size_t)NB * 4, stream);

    // ---- preferred: one persistent cooperative dispatch (static partition)
    void* args[] = {(void*)&node_f, (void*)&sidx, (void*)&sval, (void*)&out,
                    (void*)&k_self, (void*)&k_neigh, (void*)&idx2, (void*)&bfill,
                    (void*)&buckets, (void*)&fill, (void*)&csr, (void*)&ass_a,
                    (void*)&ann_a, (void*)&ass_b, (void*)&ann_b, (void*)&fb_a,
                    (void*)&fb_b};
    hipError_t err = hipLaunchCooperativeKernel(
        bf ? (const void*)fused_gat<1> : (const void*)fused_gat<0>,
        dim3(GRID), dim3(256), args, 0, stream);
    if (err == hipSuccess) return;

    // ---- fallback: legacy 6-dispatch pipeline
    if (bf) {
        l0_phase1<1><<<P1 + GB, 256, 0, stream>>>(node_f, sidx, sval, out, fb_a,
                                                  k_self, k_neigh, ass_a, ann_a,
                                                  idx2, bfill, buckets);
        bucket2csr_k<<<NB, 256, 0, stream>>>(bfill, buckets, fill, csr);
        gat_layer<1><<<GB, 256, 0, stream>>>(out, 0, fill, csr, ass_a, ann_a,
                                             fb_a, fb_b, k_self, k_neigh,
                                             ass_b, ann_b, 1);
        gat_layer<1><<<GB, 256, 0, stream>>>(out, 1, fill, csr, ass_b, ann_b,
                                             fb_b, fb_a, k_self, k_neigh,
                                             ass_a, ann_a, 1);
        gat_layer<1><<<GB, 256, 0, stream>>>(out, 2, fill, csr, ass_a, ann_a,
                                             fb_a, nullptr, k_self, k_neigh,
                                             ass_b, ann_b, 0);
    } else {
        l0_phase1<0><<<P1 + GB, 256, 0, stream>>>(node_f, sidx, sval, out, nullptr,
                                                  k_self, k_neigh, ass_a, ann_a,
                                                  idx2, bfill, buckets);
        bucket2csr_k<<<NB, 256, 0, stream>>>(bfill, buckets, fill, csr);
        gat_layer<0><<<GB, 256, 0, stream>>>(out, 0, fill, csr, ass_a, ann_a,
                                             nullptr, nullptr, k_self, k_neigh,
                                             ass_b, ann_b, 1);
        gat_layer<0><<<GB, 256, 0, stream>>>(out, 1, fill, csr, ass_b, ann_b,
                                             nullptr, nullptr, k_self, k_neigh,
                                             ass_a, ann_a, 1);
        gat_layer<0><<<GB, 256, 0, stream>>>(out, 2, fill, csr, ass_a, ann_a,
                                             nullptr, nullptr, k_self, k_neigh,
                                             ass_b, ann_b, 0);
    }
}

// Round 4
// 229.320 us; speedup vs baseline: 8.8416x; 8.8416x over previous
//
#include <hip/hip_runtime.h>
#include <math.h>

#define NN 50000
#define FF 96
#define EE 800000
#define OF 384          // 4 * FF concatenated output width
#define GB 3125         // 16 rows per block
#define FBU 48          // uints per bf16 feature row (96 bf16 = 192 B)
#define CAP 64          // slots per row (max deg ~35 for this graph)
#define NB 196          // row buckets (256 rows each; bucket = row >> 8)
#define BCAP 4608       // slots per bucket (mean 4096, +8 sigma safe)
#define CHUNK 4082      // edges per phase-1 block (196 * 4082 >= EE)
#define SHARD 12500     // col shard width: 4 shards x 2.4 MB bf16 rows (XCD L2)

__device__ __forceinline__ float grp_sum(float v) {          // 16-lane group
    for (int m = 8; m >= 1; m >>= 1) v += __shfl_xor(v, m, 64);
    return v;
}
__device__ __forceinline__ float grp_max(float v) {
    for (int m = 8; m >= 1; m >>= 1) v = fmaxf(v, __shfl_xor(v, m, 64));
    return v;
}
__device__ __forceinline__ float lrelu(float x) { return x > 0.f ? x : 0.2f * x; }
__device__ __forceinline__ void online_upd(float s, float& m, float& d) {
    float nm = fmaxf(m, s);
    d = d * __expf(m - nm) + __expf(s - nm);
    m = nm;
}
// bf16 pack/unpack (uint k holds elems 2k lo16, 2k+1 hi16; RNE rounding)
__device__ __forceinline__ float bf_lo(unsigned u) { return __uint_as_float(u << 16); }
__device__ __forceinline__ float bf_hi(unsigned u) { return __uint_as_float(u & 0xffff0000u); }
__device__ __forceinline__ unsigned pack_bf(float a, float b) {
    unsigned ua = __float_as_uint(a), ub = __float_as_uint(b);
    ua = ua + 0x7fffu + ((ua >> 16) & 1u);
    ub = ub + 0x7fffu + ((ub >> 16) & 1u);
    return (ua >> 16) | (ub & 0xffff0000u);
}

// lane lg (<12) holds row elems 8lg..8lg+7 (two float4s / one uint4)
__device__ __forceinline__ float grp_dot8(const float* a,
                                          const float* __restrict__ kf, int lg) {
    float s = 0.f;
    if (lg < 12) {
        float4 w0 = ((const float4*)kf)[2 * lg];
        float4 w1 = ((const float4*)kf)[2 * lg + 1];
        s = a[0] * w0.x + a[1] * w0.y + a[2] * w0.z + a[3] * w0.w +
            a[4] * w1.x + a[5] * w1.y + a[6] * w1.z + a[7] * w1.w;
    }
    return grp_sum(s);
}

// ---- merged: phase-1 edge bucketing (blocks < NB) + layer0 (blocks >= NB) -
// p1 blocks FIRST: the 196 long, atomic-heavy bucketing blocks launch at t=0
// and overlap the 3125 short layer-0 blocks (round 0 ran them last, so the
// dispatch was t(l0) + t(p1) serialized). Bucket geometry is round-0's
// proven 196/4608 (round 1's 782 buckets caused 15x more bfill atomics).
template<int BF>
__global__ __launch_bounds__(256) void l0_phase1(const float* __restrict__ node_f,
                                                 const int* __restrict__ sidx,
                                                 const float* __restrict__ sval,
                                                 float* __restrict__ out,
                                                 unsigned* __restrict__ fb,
                                                 const float* __restrict__ ks,
                                                 const float* __restrict__ kn,
                                                 float2* __restrict__ ass,
                                                 float2* __restrict__ ann,
                                                 const int2* __restrict__ idx2,
                                                 int* __restrict__ bfill,
                                                 unsigned* __restrict__ buckets) {
    __shared__ int cnt[NB], basearr[NB], ofs[NB];
    int tid = threadIdx.x;
    if (blockIdx.x < NB) {                    // ---- phase-1 bucketing
        int p = blockIdx.x;
        int start = p * CHUNK, end = min(start + CHUNK, EE);
        if (tid < NB) { cnt[tid] = 0; ofs[tid] = 0; }
        __syncthreads();
        for (int e = start + tid; e < end; e += 256)
            atomicAdd(&cnt[idx2[e].x >> 8], 1);
        __syncthreads();
        if (tid < NB)
            basearr[tid] = cnt[tid] ? atomicAdd(&bfill[tid], cnt[tid]) : 0;
        __syncthreads();
        for (int e = start + tid; e < end; e += 256) {
            int2 q = idx2[e];
            int b = q.x >> 8;
            int slot = basearr[b] + atomicAdd(&ofs[b], 1);
            if (slot < BCAP)
                buckets[(size_t)b * BCAP + slot] =
                    ((unsigned)(q.x & 255) << 16) | (unsigned)q.y;
        }
        return;
    }
    // ---- layer 0: relu(self_val * node_f) + fused dots + bf16 copy
    int g = tid >> 4, lg = tid & 15;
    int n = (blockIdx.x - NB) * 16 + g;
    if (n >= NN) return;
    int sr = sidx[2 * n];
    int sc = sidx[2 * n + 1];
    float v = sval[n];
    float a[8] = {0.f, 0.f, 0.f, 0.f, 0.f, 0.f, 0.f, 0.f};
    if (lg < 12) {
        const float4* xr4 = (const float4*)(node_f + (size_t)sc * FF);
        float4 x0 = xr4[2 * lg], x1 = xr4[2 * lg + 1];
        a[0] = fmaxf(v * x0.x, 0.f); a[1] = fmaxf(v * x0.y, 0.f);
        a[2] = fmaxf(v * x0.z, 0.f); a[3] = fmaxf(v * x0.w, 0.f);
        a[4] = fmaxf(v * x1.x, 0.f); a[5] = fmaxf(v * x1.y, 0.f);
        a[6] = fmaxf(v * x1.z, 0.f); a[7] = fmaxf(v * x1.w, 0.f);
        float4* op4 = (float4*)(out + (size_t)sr * OF);
        op4[2 * lg]     = make_float4(a[0], a[1], a[2], a[3]);
        op4[2 * lg + 1] = make_float4(a[4], a[5], a[6], a[7]);
        if (BF) {
            uint4 p;
            p.x = pack_bf(a[0], a[1]); p.y = pack_bf(a[2], a[3]);
            p.z = pack_bf(a[4], a[5]); p.w = pack_bf(a[6], a[7]);
            ((uint4*)(fb + (size_t)sr * FBU))[lg] = p;
        }
    }
    float p0 = grp_dot8(a, ks, lg);
    float p1 = grp_dot8(a, ks + FF, lg);
    float p2 = grp_dot8(a, kn, lg);
    float p3 = grp_dot8(a, kn + FF, lg);
    if (lg == 0) {
        ass[sr] = make_float2(p0, p1);
        ann[sr] = make_float2(p2, p3);
    }
}

// ---- phase 2: per-bucket LDS placement, neighbors sorted by col shard -----
// Storage order by shard => during gat pass B the whole grid sweeps shard 0,
// then 1,2,3; each shard's 2.4 MB of bf16 rows stays XCD-L2 resident.
// (Earlier round measured: FETCH 126 -> 45 MB per gat dispatch.)
__global__ __launch_bounds__(256) void bucket2csr(const int* __restrict__ bfill,
                                                  const unsigned* __restrict__ buckets,
                                                  int* __restrict__ fill,
                                                  unsigned short* __restrict__ csr) {
    __shared__ unsigned short lcsr[256 * CAP];   // 32 KB
    __shared__ int lcnt[256 * 4], loff[256 * 4]; // 8 KB
    int tid = threadIdx.x, b = blockIdx.x;
#pragma unroll
    for (int c = 0; c < 4; ++c) lcnt[tid * 4 + c] = 0;
    __syncthreads();
    int cnt = min(bfill[b], BCAP);
    const unsigned* bp = buckets + (size_t)b * BCAP;
    for (int i = tid; i < cnt; i += 256) {       // pass 1: count per (row,shard)
        unsigned u = bp[i];
        atomicAdd(&lcnt[(u >> 16) * 4 + (int)((u & 0xffffu) / SHARD)], 1);
    }
    __syncthreads();
    {
        int c0 = lcnt[tid * 4], c1 = lcnt[tid * 4 + 1];
        int c2 = lcnt[tid * 4 + 2], c3 = lcnt[tid * 4 + 3];
        loff[tid * 4] = 0;
        loff[tid * 4 + 1] = c0;
        loff[tid * 4 + 2] = c0 + c1;
        loff[tid * 4 + 3] = c0 + c1 + c2;
        int r = b * 256 + tid;
        if (r < NN) fill[r] = min(c0 + c1 + c2 + c3, CAP);
        lcnt[tid * 4] = 0; lcnt[tid * 4 + 1] = 0;
        lcnt[tid * 4 + 2] = 0; lcnt[tid * 4 + 3] = 0;
    }
    __syncthreads();
    for (int i = tid; i < cnt; i += 256) {       // pass 2: shard-sorted place
        unsigned u = bp[i];
        int lr = u >> 16, col = u & 0xffffu, cls = col / SHARD;
        int pos = loff[lr * 4 + cls] + atomicAdd(&lcnt[lr * 4 + cls], 1);
        if (pos < CAP) lcsr[lr * CAP + pos] = (unsigned short)col;
    }
    __syncthreads();
    const uint4* src = (const uint4*)lcsr;
    uint4* dst = (uint4*)(csr + (size_t)b * 256 * CAP);
    for (int i = tid; i < 256 * CAP / 8; i += 256) dst[i] = src[i];
}

// ---- aggregation helper: one dwordx4 per edge per lane (lanes 0-11) -------
// unroll 8 => up to 8 independent 16B gathers in flight per group
template<int BF>
__device__ __forceinline__ void agg_chunk(float cj, int colj, int nj, int gbase,
                                          const float* __restrict__ feats,
                                          const unsigned* __restrict__ fb, int lg,
                                          float* a) {
#pragma unroll 8
    for (int k = 0; k < nj; ++k) {
        float cc = __shfl(cj, gbase + k, 64);
        int col  = __shfl(colj, gbase + k, 64);
        if (lg < 12) {
            if (BF) {
                uint4 q = ((const uint4*)(fb + (size_t)col * FBU))[lg];
                a[0] += cc * bf_lo(q.x); a[1] += cc * bf_hi(q.x);
                a[2] += cc * bf_lo(q.y); a[3] += cc * bf_hi(q.y);
                a[4] += cc * bf_lo(q.z); a[5] += cc * bf_hi(q.z);
                a[6] += cc * bf_lo(q.w); a[7] += cc * bf_hi(q.w);
            } else {
                const float4* vp = (const float4*)(feats + (size_t)col * OF);
                float4 v0 = vp[2 * lg], v1 = vp[2 * lg + 1];
                a[0] += cc * v0.x; a[1] += cc * v0.y;
                a[2] += cc * v0.z; a[3] += cc * v0.w;
                a[4] += cc * v1.x; a[5] += cc * v1.y;
                a[6] += cc * v1.z; a[7] += cc * v1.w;
            }
        }
    }
}

// ---- main GAT layer: 16-lane group per destination row --------------------
template<int BF>
__global__ __launch_bounds__(256) void gat_layer(float* __restrict__ out, int l,
                                                 const int* __restrict__ fill,
                                                 const unsigned short* __restrict__ csr,
                                                 const float2* __restrict__ ass,
                                                 const float2* __restrict__ ann,
                                                 const unsigned* __restrict__ fb_in,
                                                 unsigned* __restrict__ fb_out,
                                                 const float* __restrict__ ks,
                                                 const float* __restrict__ kn,
                                                 float2* __restrict__ ass_out,
                                                 float2* __restrict__ ann_out,
                                                 int write_dots) {
    int tid = threadIdx.x;
    int g = tid >> 4, lg = tid & 15;
    int gbase = (g & 3) * 16;                 // group base lane within wave
    int r = blockIdx.x * 16 + g;
    if (r >= NN) return;
    int deg = fill[r];
    const unsigned short* crow = csr + (size_t)r * CAP;
    const float* feats = out + l * FF;        // fp32 fallback source
    float2 as_r = ass[r];

    // ---- pass A: scores; chunks 0,1 (deg<=32, ~all rows) cached in scalars
    float m0 = -1e30f, m1 = -1e30f, d0 = 0.f, d1 = 0.f;
    int   c0col = 0, c1col = 0;
    float c0s0 = -1e30f, c0s1 = -1e30f, c1s0 = -1e30f, c1s1 = -1e30f;
    if (lg < deg) {
        int c = crow[lg];
        float2 an = ann[c];
        c0col = c;
        c0s0 = lrelu(as_r.x + an.x);
        c0s1 = lrelu(as_r.y + an.y);
        online_upd(c0s0, m0, d0);
        online_upd(c0s1, m1, d1);
    }
    if (deg > 16) {
        int j = 16 + lg;
        if (j < deg) {
            int c = crow[j];
            float2 an = ann[c];
            c1col = c;
            c1s0 = lrelu(as_r.x + an.x);
            c1s1 = lrelu(as_r.y + an.y);
            online_upd(c1s0, m0, d0);
            online_upd(c1s1, m1, d1);
        }
        for (int j0 = 32; j0 < deg; j0 += 16) {
            int jj = j0 + lg;
            if (jj < deg) {
                int c = crow[jj];
                float2 an = ann[c];
                online_upd(lrelu(as_r.x + an.x), m0, d0);
                online_upd(lrelu(as_r.y + an.y), m1, d1);
            }
        }
    }
    float M0 = grp_max(m0), M1 = grp_max(m1);
    d0 = grp_sum(d0 * __expf(m0 - M0));
    d1 = grp_sum(d1 * __expf(m1 - M1));
    float inv0 = d0 > 0.f ? 0.5f / d0 : 0.f;  // 0.5 = mean over 2 heads
    float inv1 = d1 > 0.f ? 0.5f / d1 : 0.f;

    // ---- pass B: aggregate (one 16B load per edge per lane, lanes 0-11)
    float a[8] = {0.f, 0.f, 0.f, 0.f, 0.f, 0.f, 0.f, 0.f};
    {
        float cj = __expf(c0s0 - M0) * inv0 + __expf(c0s1 - M1) * inv1;
        agg_chunk<BF>(cj, c0col, min(deg, 16), gbase, feats, fb_in, lg, a);
    }
    if (deg > 16) {
        float cj = __expf(c1s0 - M0) * inv0 + __expf(c1s1 - M1) * inv1;
        agg_chunk<BF>(cj, c1col, min(deg - 16, 16), gbase, feats, fb_in, lg, a);
        for (int j0 = 32; j0 < deg; j0 += 16) {
            float cjr = 0.f; int colr = 0;
            int jj = j0 + lg;
            if (jj < deg) {
                int c = crow[jj];
                float2 an = ann[c];
                cjr = __expf(lrelu(as_r.x + an.x) - M0) * inv0 +
                      __expf(lrelu(as_r.y + an.y) - M1) * inv1;
                colr = c;
            }
            agg_chunk<BF>(cjr, colr, min(deg - j0, 16), gbase, feats, fb_in, lg, a);
        }
    }

#pragma unroll
    for (int i = 0; i < 8; ++i) a[i] = fmaxf(a[i], 0.f);
    if (lg < 12) {
        float4* op4 = (float4*)(out + (size_t)r * OF + (l + 1) * FF);
        op4[2 * lg]     = make_float4(a[0], a[1], a[2], a[3]);
        op4[2 * lg + 1] = make_float4(a[4], a[5], a[6], a[7]);
        if (BF && fb_out) {
            uint4 p;
            p.x = pack_bf(a[0], a[1]); p.y = pack_bf(a[2], a[3]);
            p.z = pack_bf(a[4], a[5]); p.w = pack_bf(a[6], a[7]);
            ((uint4*)(fb_out + (size_t)r * FBU))[lg] = p;
        }
    }

    if (write_dots) {
        float p0 = grp_dot8(a, ks, lg);
        float p1 = grp_dot8(a, ks + FF, lg);
        float p2 = grp_dot8(a, kn, lg);
        float p3 = grp_dot8(a, kn + FF, lg);
        if (lg == 0) {
            ass_out[r] = make_float2(p0, p1);
            ann_out[r] = make_float2(p2, p3);
        }
    }
}

extern "C" void kernel_launch(void* const* d_in, const int* in_sizes, int n_in,
                              void* d_out, int out_size, void* d_ws, size_t ws_size,
                              hipStream_t stream) {
    const float* node_f  = (const float*)d_in[0];
    const int*   adj_idx = (const int*)d_in[1];   // (1,E,2) [row,col] int32
    const int*   sidx    = (const int*)d_in[2];   // (N,2)
    const float* sval    = (const float*)d_in[3]; // (N,)
    const float* k_self  = (const float*)d_in[4]; // (2,96)
    const float* k_neigh = (const float*)d_in[5]; // (2,96)
    float* out = (float*)d_out;                   // (N, 384)

    char* w = (char*)d_ws;
    auto alloc = [&](size_t bytes) {
        char* p = w;
        w += (bytes + 255) & ~(size_t)255;
        return p;
    };
    int*            fill    = (int*)alloc((size_t)NN * 4);
    unsigned short* csr     = (unsigned short*)alloc((size_t)NB * 256 * CAP * 2);
    int*            bfill   = (int*)alloc((size_t)NB * 4);
    unsigned*       buckets = (unsigned*)alloc((size_t)NB * BCAP * 4);
    float2*         ass_a   = (float2*)alloc((size_t)NN * 8);
    float2*         ann_a   = (float2*)alloc((size_t)NN * 8);
    float2*         ass_b   = (float2*)alloc((size_t)NN * 8);
    float2*         ann_b   = (float2*)alloc((size_t)NN * 8);
    unsigned*       fb_a    = (unsigned*)alloc((size_t)NN * FBU * 4);
    unsigned*       fb_b    = (unsigned*)alloc((size_t)NN * FBU * 4);
    // bf16-gather path only if the workspace actually holds the two fb buffers
    bool bf = (size_t)(w - (char*)d_ws) <= ws_size;

    hipMemsetAsync(bfill, 0, (size_t)NB * 4, stream);

    if (bf) {
        l0_phase1<1><<<NB + GB, 256, 0, stream>>>(node_f, sidx, sval, out, fb_a,
                                                  k_self, k_neigh, ass_a, ann_a,
                                                  (const int2*)adj_idx, bfill, buckets);
        bucket2csr<<<NB, 256, 0, stream>>>(bfill, buckets, fill, csr);
        gat_layer<1><<<GB, 256, 0, stream>>>(out, 0, fill, csr, ass_a, ann_a,
                                             fb_a, fb_b, k_self, k_neigh,
                                             ass_b, ann_b, 1);
        gat_layer<1><<<GB, 256, 0, stream>>>(out, 1, fill, csr, ass_b, ann_b,
                                             fb_b, fb_a, k_self, k_neigh,
                                             ass_a, ann_a, 1);
        gat_layer<1><<<GB, 256, 0, stream>>>(out, 2, fill, csr, ass_a, ann_a,
                                             fb_a, nullptr, k_self, k_neigh,
                                             ass_b, ann_b, 0);
    } else {
        l0_phase1<0><<<NB + GB, 256, 0, stream>>>(node_f, sidx, sval, out, nullptr,
                                                  k_self, k_neigh, ass_a, ann_a,
                                                  (const int2*)adj_idx, bfill, buckets);
        bucket2csr<<<NB, 256, 0, stream>>>(bfill, buckets, fill, csr);
        gat_layer<0><<<GB, 256, 0, stream>>>(out, 0, fill, csr, ass_a, ann_a,
                                             nullptr, nullptr, k_self, k_neigh,
                                             ass_b, ann_b, 1);
        gat_layer<0><<<GB, 256, 0, stream>>>(out, 1, fill, csr, ass_b, ann_b,
                                             nullptr, nullptr, k_self, k_neigh,
                                             ass_a, ann_a, 1);
        gat_layer<0><<<GB, 256, 0, stream>>>(out, 2, fill, csr, ass_a, ann_a,
                                             nullptr, nullptr, k_self, k_neigh,
                                             ass_b, ann_b, 0);
    }
}